// Round 5
// baseline (565.045 us; speedup 1.0000x reference)
//
#include <hip/hip_runtime.h>
#include <utility>

#define NUM_NET 2
#define V 100000
#define D 128
#define B 4096
#define K 5
#define NS 10

// weight magnitude classes (sign is folded into the logsigmoid argument)
#define W_A (1.0f/20480.0f)   // 1/(B*K)      main pos
#define W_B (1.0f/4096.0f)    // 1/B          neg_main
#define W_C (0.1f/4096.0f)    // HYP/B        node/cross-neg/role
#define W_D (0.1f/20480.0f)   // HYP2/(B*K)   cross pos

#define NBINS 64
#define NENT  (8192*143)      // 1,171,456 (ctx,node) dot entries
#define NBUCK 4096            // (tab<<10)|(idx>>7): 128-row / 64 KB buckets
// workspace layout (byte offsets)
#define OFF_HIST   1024
#define OFF_OFF    20480
#define OFF_CUR    40960
#define OFF_ENT    65536
#define WS_NEEDED  (65536ULL + (unsigned long long)NENT*8ULL)

typedef unsigned int u32;
typedef unsigned long long u64;

// ---- compile-time for-loop ----
template <class F, int... Is>
__device__ __forceinline__ void sfor_impl(F&& f, std::integer_sequence<int, Is...>) {
    (f(std::integral_constant<int, Is>{}), ...);
}
template <int N, class F>
__device__ __forceinline__ void sfor(F&& f) {
    sfor_impl((F&&)f, std::make_integer_sequence<int, N>{});
}

// DPP-based add: v + dpp_perm(v). 0xB1=quad xor1, 0x4E=quad xor2,
// 0x124=row_ror:4, 0x128=row_ror:8  -> full 16-lane row sum in all lanes.
template <int CTRL>
__device__ __forceinline__ float dpp_xadd(float v) {
    int r = __builtin_amdgcn_update_dpp(0, __float_as_int(v), CTRL, 0xF, 0xF, true);
    return v + __int_as_float(r);
}

__device__ __forceinline__ float lsig(float x) {
    return fminf(x, 0.0f) - __logf(1.0f + __expf(-fabsf(x)));
}

// ---- entry enumeration: g in [0, NENT) -> (idx, tab, cls) + unit ----
// tab: 0/1 = node_tables net0/1, 2/3 = neigh_tables net0/1
// cls: 0:A+  1:B-  2:C+  3:C-  4:D+   (bit0 = negate dot)
__device__ __forceinline__ void enum_entry(
    u32 g, const int* nodes_idx, const int* neigh_idx, const int* role_idx,
    const int* neg_main, const int* neg_node, const int* neg_cross,
    const int* neg_role, int& idx, int& tab, int& cls, int& unit)
{
    unit = g / 143u;
    int d = g - unit*143u;
    int i = unit >> 12, b = unit & (B-1), j = 1 - i;
    if      (d <   5) { idx = neigh_idx[(i*B+b)*K + d];             tab = 2+i; cls = 0; }
    else if (d <  55) { idx = neg_main[(i*B+b)*50 + (d-5)];         tab = 2+i; cls = 1; }
    else if (d <  56) { idx = nodes_idx[i*B+b];                     tab = j;   cls = 2; }
    else if (d <  66) { idx = neg_node[((i*2+j)*B+b)*NS + (d-56)];  tab = j;   cls = 3; }
    else if (d <  71) { idx = neigh_idx[(i*B+b)*K + (d-66)];        tab = 2+j; cls = 4; }
    else if (d < 121) { idx = neg_cross[((i*2+j)*B+b)*50 + (d-71)]; tab = 2+j; cls = 3; }
    else if (d < 122) { idx = role_idx[(i*2+0)*B+b];                tab = 0;   cls = 2; }
    else if (d < 132) { idx = neg_role[((i*2+0)*B+b)*NS + (d-122)]; tab = 0;   cls = 3; }
    else if (d < 133) { idx = role_idx[(i*2+1)*B+b];                tab = 1;   cls = 2; }
    else              { idx = neg_role[((i*2+1)*B+b)*NS + (d-133)]; tab = 1;   cls = 3; }
}

// ---- pass 1: bucket histogram ----
__global__ __launch_bounds__(256) void rmne_hist(
    const int* __restrict__ nodes_idx, const int* __restrict__ neigh_idx,
    const int* __restrict__ role_idx,  const int* __restrict__ neg_main,
    const int* __restrict__ neg_node,  const int* __restrict__ neg_cross,
    const int* __restrict__ neg_role,  u32* __restrict__ hist)
{
    u32 g = blockIdx.x*256 + threadIdx.x;
    if (g >= NENT) return;
    int idx, tab, cls, unit;
    enum_entry(g, nodes_idx, neigh_idx, role_idx, neg_main, neg_node,
               neg_cross, neg_role, idx, tab, cls, unit);
    atomicAdd(&hist[(tab<<10) | (idx>>7)], 1u);
}

// ---- pass 2: exclusive scan of 4096 buckets (1 block, 1024 threads) ----
__global__ __launch_bounds__(1024) void rmne_scan(
    const u32* __restrict__ hist, u32* __restrict__ off, u32* __restrict__ cur)
{
    const u32 t = threadIdx.x, lane = t & 63, w = t >> 6;
    u32 v0 = hist[4*t], v1 = hist[4*t+1], v2 = hist[4*t+2], v3 = hist[4*t+3];
    u32 s = v0+v1+v2+v3;
    // wave inclusive scan
    u32 v = s;
    #pragma unroll
    for (int dlt = 1; dlt <= 32; dlt <<= 1) {
        u32 u = __shfl_up(v, dlt, 64);
        if (lane >= (u32)dlt) v += u;
    }
    __shared__ u32 p[16];
    if (lane == 63) p[w] = v;
    __syncthreads();
    if (w == 0) {
        u32 pv = (lane < 16) ? p[lane] : 0;
        u32 pi = pv;
        #pragma unroll
        for (int dlt = 1; dlt <= 8; dlt <<= 1) {
            u32 u = __shfl_up(pi, dlt, 64);
            if (lane >= (u32)dlt) pi += u;
        }
        if (lane < 16) p[lane] = pi - pv;   // exclusive wave offsets
    }
    __syncthreads();
    u32 base = p[w] + v - s;                // block-exclusive for this thread
    off[4*t]   = base;          cur[4*t]   = base;
    off[4*t+1] = base+v0;       cur[4*t+1] = base+v0;
    off[4*t+2] = base+v0+v1;    cur[4*t+2] = base+v0+v1;
    off[4*t+3] = base+v0+v1+v2; cur[4*t+3] = base+v0+v1+v2;
    if (t == 1023) off[4096] = base + s;
}

// ---- pass 3: scatter packed entries into bucket order ----
// entry: [0:17) idx | [17:19) tab | [19:37) nrowg=(net<<17|nrow) | [37:40) cls
__global__ __launch_bounds__(256) void rmne_scatter(
    const int* __restrict__ nodes_idx, const int* __restrict__ neigh_idx,
    const int* __restrict__ role_idx,  const int* __restrict__ neg_main,
    const int* __restrict__ neg_node,  const int* __restrict__ neg_cross,
    const int* __restrict__ neg_role,  u32* __restrict__ cur,
    u64* __restrict__ entries)
{
    u32 g = blockIdx.x*256 + threadIdx.x;
    if (g >= NENT) return;
    int idx, tab, cls, unit;
    enum_entry(g, nodes_idx, neigh_idx, role_idx, neg_main, neg_node,
               neg_cross, neg_role, idx, tab, cls, unit);
    int i = unit >> 12, b = unit & (B-1);
    int nrow = nodes_idx[i*B+b];
    u64 ent = (u64)(u32)idx | ((u64)(u32)tab << 17)
            | ((u64)(u32)((i<<17) | nrow) << 19) | ((u64)(u32)cls << 37);
    u32 pos = atomicAdd(&cur[(tab<<10) | (idx>>7)], 1u);
    entries[pos] = ent;
}

// ---- pass 4: process entries in bucket order (64 KB ctx windows) ----
__global__ __launch_bounds__(256) void rmne_proc(
    const float* __restrict__ node_tables, const float* __restrict__ neigh_tables,
    const u32* __restrict__ off, const u64* __restrict__ entries,
    float* __restrict__ ws)
{
    const u32 bucket = blockIdx.x;
    const u32 start = off[bucket], end = off[bucket+1];
    const int tid = threadIdx.x;
    const int lane = tid & 63;
    const int l16  = tid & 15;
    const int q    = tid >> 4;       // 0..15: quarter-group id within block

    float acc = 0.0f;
    for (u32 e = start + q; e < end; e += 16) {
        u64 ent = entries[e];
        int idx = (int)(ent & 0x1FFFF);
        int tab = (int)((ent >> 17) & 3);
        int ng  = (int)((ent >> 19) & 0x3FFFF);
        int cls = (int)((ent >> 37) & 7);
        const float* cbase = (tab & 2) ? neigh_tables : node_tables;
        const float4* crow = (const float4*)(cbase + ((size_t)(tab&1)*V + (size_t)idx)*D) + l16*2;
        const float4* nrow = (const float4*)(node_tables + ((size_t)(ng>>17)*V + (size_t)(ng&0x1FFFF))*D) + l16*2;
        float4 c0 = crow[0], c1 = crow[1];
        float4 n0 = nrow[0], n1 = nrow[1];
        float pp = n0.x*c0.x + n0.y*c0.y + n0.z*c0.z + n0.w*c0.w
                 + n1.x*c1.x + n1.y*c1.y + n1.z*c1.z + n1.w*c1.w;
        pp = dpp_xadd<0xB1>(pp);
        pp = dpp_xadd<0x4E>(pp);
        pp = dpp_xadd<0x124>(pp);
        pp = dpp_xadd<0x128>(pp);
        float x   = (cls & 1) ? -pp : pp;
        float mag = (cls == 0) ? W_A : (cls == 1) ? W_B : (cls == 4) ? W_D : W_C;
        acc = fmaf(mag, lsig(x), acc);
    }

    // lanes within a quarter hold identical acc; xor16+xor32 sums one rep per quarter
    acc += __shfl_xor(acc, 16, 64);
    acc += __shfl_xor(acc, 32, 64);
    __shared__ float wsum[4];
    if (lane == 0) wsum[tid >> 6] = acc;
    __syncthreads();
    if (tid == 0) {
        float s = wsum[0] + wsum[1] + wsum[2] + wsum[3];
        atomicAdd(ws + (blockIdx.x & (NBINS-1)), s);
    }
}

// ================= fallback: round-4 proven gather kernel =================
__device__ __forceinline__ void gload2(float4& d0, float4& d1, const float* addr) {
    asm volatile("global_load_dwordx4 %0, %2, off\n\t"
                 "global_load_dwordx4 %1, %2, off offset:256"
                 : "=&v"(d0), "=&v"(d1)
                 : "v"(addr)
                 : "memory");
}
template <int N>
__device__ __forceinline__ void waitfor() {
    asm volatile("s_waitcnt vmcnt(%0)" :: "i"(N) : "memory");
    __builtin_amdgcn_sched_barrier(0);
}
#define DEPTH 4
__global__ __launch_bounds__(256) void rmne_main(
    const float* __restrict__ node_tables,
    const float* __restrict__ neigh_tables,
    const int*   __restrict__ nodes_idx,
    const int*   __restrict__ neigh_idx,
    const int*   __restrict__ role_idx,
    const int*   __restrict__ neg_main,
    const int*   __restrict__ neg_node,
    const int*   __restrict__ neg_cross,
    const int*   __restrict__ neg_role,
    float*       __restrict__ ws)
{
    const int tid  = threadIdx.x;
    const int lane = tid & 63;
    const int wave = tid >> 6;
    const int unit = blockIdx.x * 4 + wave;
    const int i = unit >> 12;
    const int b = unit & (B - 1);
    const int j = 1 - i;
    int pk[3];
    #pragma unroll
    for (int s = 0; s < 3; ++s) {
        int d = lane + 64 * s;
        int idx = 0; int tab = 0;
        if      (d <   5) { idx = neigh_idx[(i*B + b)*K + d];             tab = 2 + i; }
        else if (d <  55) { idx = neg_main[(i*B + b)*50 + (d-5)];         tab = 2 + i; }
        else if (d <  56) { idx = nodes_idx[i*B + b];                     tab = j;     }
        else if (d <  66) { idx = neg_node[((i*2+j)*B + b)*NS + (d-56)];  tab = j;     }
        else if (d <  71) { idx = neigh_idx[(i*B + b)*K + (d-66)];        tab = 2 + j; }
        else if (d < 121) { idx = neg_cross[((i*2+j)*B + b)*50 + (d-71)]; tab = 2 + j; }
        else if (d < 122) { idx = role_idx[(i*2+0)*B + b];                tab = 0;     }
        else if (d < 132) { idx = neg_role[((i*2+0)*B + b)*NS + (d-122)]; tab = 0;     }
        else if (d < 133) { idx = role_idx[(i*2+1)*B + b];                tab = 1;     }
        else if (d < 143) { idx = neg_role[((i*2+1)*B + b)*NS + (d-133)]; tab = 1;     }
        pk[s] = idx | (tab << 20);
    }
    const int l16     = lane & 15;
    const int quarter = lane >> 4;
    const int nrow    = nodes_idx[i*B + b];
    const float* nep  = node_tables + ((size_t)i*V + (size_t)nrow)*D + l16*4;
    float4 c0b[DEPTH], c1b[DEPTH];
    float4 ne0, ne1;
    auto issue = [&](auto tc) {
        constexpr int T = decltype(tc)::value;
        constexpr int S = T >> 4;
        int src = (4*T + quarter) & 63;
        int p   = __shfl(pk[S], src, 64);
        int idx = p & 0xFFFFF;
        int tab = p >> 20;
        const float* base = (tab & 2) ? neigh_tables : node_tables;
        const float* addr = base + ((size_t)(tab & 1)*V + (size_t)idx)*D + l16*4;
        gload2(c0b[T & (DEPTH-1)], c1b[T & (DEPTH-1)], addr);
    };
    asm volatile("s_waitcnt vmcnt(0)" ::: "memory");
    gload2(ne0, ne1, nep);
    sfor<DEPTH>([&](auto tc) { issue(tc); });
    float accA = 0.0f, accB = 0.0f, accC = 0.0f, accG = 0.0f;
    sfor<36>([&](auto tc) {
        constexpr int T   = decltype(tc)::value;
        constexpr int INF = (36 - T) < DEPTH ? (36 - T) : DEPTH;
        waitfor<2*(INF-1)>();
        float4 c0 = c0b[T & (DEPTH-1)];
        float4 c1 = c1b[T & (DEPTH-1)];
        float pp = ne0.x*c0.x + ne0.y*c0.y + ne0.z*c0.z + ne0.w*c0.w
                 + ne1.x*c1.x + ne1.y*c1.y + ne1.z*c1.z + ne1.w*c1.w;
        pp = dpp_xadd<0xB1>(pp);
        pp = dpp_xadd<0x4E>(pp);
        pp = dpp_xadd<0x124>(pp);
        pp = dpp_xadd<0x128>(pp);
        if constexpr (T == 0) { accA += lsig(pp); }
        else if constexpr (T == 1) {
            float x  = (quarter == 0) ? pp : -pp;
            float mw = (quarter == 0) ? W_A : W_B;
            accG = fmaf(mw, lsig(x), accG);
        } else if constexpr (T <= 12) { accB += lsig(-pp); }
        else if constexpr (T == 13) {
            float x  = (quarter == 3) ? pp : -pp;
            float mw = (quarter == 3) ? W_C : W_B;
            accG = fmaf(mw, lsig(x), accG);
        } else if constexpr (T <= 15) { accC += lsig(-pp); }
        else if constexpr (T == 16) {
            float x  = (quarter >= 2) ? pp : -pp;
            float mw = (quarter >= 2) ? W_D : W_C;
            accG = fmaf(mw, lsig(x), accG);
        } else if constexpr (T == 17) {
            float x  = (quarter == 3) ? -pp : pp;
            float mw = (quarter == 3) ? W_C : W_D;
            accG = fmaf(mw, lsig(x), accG);
        } else if constexpr (T <= 29) { accC += lsig(-pp); }
        else if constexpr (T == 30) {
            float x = (quarter == 1) ? pp : -pp;
            accC += lsig(x);
        } else if constexpr (T <= 32) { accC += lsig(-pp); }
        else if constexpr (T == 33) {
            float x = (quarter == 0) ? pp : -pp;
            accC += lsig(x);
        } else if constexpr (T == 34) { accC += lsig(-pp); }
        else {
            float ls = lsig(-pp);
            accC += (quarter == 3) ? 0.0f : ls;
        }
        if constexpr (T + DEPTH < 36) issue(std::integral_constant<int, T + DEPTH>{});
    });
    float acc = W_A*accA + W_B*accB + W_C*accC + accG;
    acc += __shfl_xor(acc, 16, 64);
    acc += __shfl_xor(acc, 32, 64);
    __shared__ float wsum[4];
    if (lane == 0) wsum[wave] = acc;
    __syncthreads();
    if (tid == 0) {
        float s = wsum[0] + wsum[1] + wsum[2] + wsum[3];
        atomicAdd(ws + (blockIdx.x & (NBINS - 1)), s);
    }
}

__global__ void rmne_finalize(const float* __restrict__ ws, float* __restrict__ out)
{
    float v = ws[threadIdx.x];
    v += __shfl_xor(v, 1, 64);
    v += __shfl_xor(v, 2, 64);
    v += __shfl_xor(v, 4, 64);
    v += __shfl_xor(v, 8, 64);
    v += __shfl_xor(v, 16, 64);
    v += __shfl_xor(v, 32, 64);
    if (threadIdx.x == 0) out[0] = v * (-1.0f / 10.0f);
}

extern "C" void kernel_launch(void* const* d_in, const int* in_sizes, int n_in,
                              void* d_out, int out_size, void* d_ws, size_t ws_size,
                              hipStream_t stream) {
    const float* node_tables  = (const float*)d_in[0];
    const float* neigh_tables = (const float*)d_in[1];
    const int*   nodes_idx    = (const int*)d_in[2];
    const int*   neigh_idx    = (const int*)d_in[3];
    const int*   role_idx     = (const int*)d_in[4];
    const int*   neg_main     = (const int*)d_in[5];
    const int*   neg_node     = (const int*)d_in[6];
    const int*   neg_cross    = (const int*)d_in[7];
    const int*   neg_role     = (const int*)d_in[8];
    float* out = (float*)d_out;

    if (ws_size >= WS_NEEDED) {
        char* wsb = (char*)d_ws;
        float* bins   = (float*)wsb;
        u32*   hist   = (u32*)(wsb + OFF_HIST);
        u32*   off    = (u32*)(wsb + OFF_OFF);
        u32*   cur    = (u32*)(wsb + OFF_CUR);
        u64*   ents   = (u64*)(wsb + OFF_ENT);
        hipMemsetAsync(d_ws, 0, OFF_ENT, stream);
        const int EB = (NENT + 255) / 256;
        rmne_hist<<<EB, 256, 0, stream>>>(nodes_idx, neigh_idx, role_idx, neg_main,
                                          neg_node, neg_cross, neg_role, hist);
        rmne_scan<<<1, 1024, 0, stream>>>(hist, off, cur);
        rmne_scatter<<<EB, 256, 0, stream>>>(nodes_idx, neigh_idx, role_idx, neg_main,
                                             neg_node, neg_cross, neg_role, cur, ents);
        rmne_proc<<<NBUCK, 256, 0, stream>>>(node_tables, neigh_tables, off, ents, bins);
        rmne_finalize<<<1, 64, 0, stream>>>(bins, out);
    } else {
        float* ws = (float*)d_ws;
        hipMemsetAsync(ws, 0, NBINS * sizeof(float), stream);
        rmne_main<<<2048, 256, 0, stream>>>(node_tables, neigh_tables, nodes_idx, neigh_idx,
                                            role_idx, neg_main, neg_node, neg_cross, neg_role, ws);
        rmne_finalize<<<1, 64, 0, stream>>>(ws, out);
    }
}

// Round 6
// 256.810 us; speedup vs baseline: 2.2002x; 2.2002x over previous
//
#include <hip/hip_runtime.h>

#define NUM_NET 2
#define V 100000
#define D 128
#define B 4096
#define K 5
#define NS 10

// weight magnitude classes (sign is folded into the logsigmoid argument)
#define W_A (1.0f/20480.0f)   // 1/(B*K)      main pos
#define W_B (1.0f/4096.0f)    // 1/B          neg_main
#define W_C (0.1f/4096.0f)    // HYP/B        node/cross-neg/role
#define W_D (0.1f/20480.0f)   // HYP2/(B*K)   cross pos

#define NBINS 64
#define PIPE 4

// DPP-based add: v + dpp_perm(v). CTRL: 0xB1=quad_perm(1,0,3,2) (xor1),
// 0x4E=quad_perm(2,3,0,1) (xor2), 0x124=row_ror:4, 0x128=row_ror:8.
template <int CTRL>
__device__ __forceinline__ float dpp_xadd(float v) {
    int r = __builtin_amdgcn_update_dpp(0, __float_as_int(v), CTRL, 0xF, 0xF, true);
    return v + __int_as_float(r);
}

__device__ __forceinline__ float lsig(float x) {
    return fminf(x, 0.0f) - __logf(1.0f + __expf(-fabsf(x)));
}

__global__ __launch_bounds__(256) void rmne_main(
    const float* __restrict__ node_tables,
    const float* __restrict__ neigh_tables,
    const int*   __restrict__ nodes_idx,
    const int*   __restrict__ neigh_idx,
    const int*   __restrict__ role_idx,
    const int*   __restrict__ neg_main,
    const int*   __restrict__ neg_node,
    const int*   __restrict__ neg_cross,
    const int*   __restrict__ neg_role,
    float*       __restrict__ ws)
{
    const int tid  = threadIdx.x;
    const int lane = tid & 63;
    const int wave = tid >> 6;
    const int unit = blockIdx.x * 4 + wave;   // 8192 units total
    const int i = unit >> 12;                 // net index (0/1)
    const int b = unit & (B - 1);
    const int j = 1 - i;

    // ---- 144-entry (idx|tab) list in 3 per-lane register slots ----
    // d = lane + 64*s; d==143 is a zero-weight pad (skipped at consume).
    int pk[3];
    #pragma unroll
    for (int s = 0; s < 3; ++s) {
        int d = lane + 64 * s;
        int idx = 0; int tab = 0;  // tab: 0/1 node net, 2/3 neigh net
        if      (d <   5) { idx = neigh_idx[(i*B + b)*K + d];             tab = 2 + i; }
        else if (d <  55) { idx = neg_main[(i*B + b)*50 + (d-5)];         tab = 2 + i; }
        else if (d <  56) { idx = nodes_idx[i*B + b];                     tab = j;     }
        else if (d <  66) { idx = neg_node[((i*2+j)*B + b)*NS + (d-56)];  tab = j;     }
        else if (d <  71) { idx = neigh_idx[(i*B + b)*K + (d-66)];        tab = 2 + j; }
        else if (d < 121) { idx = neg_cross[((i*2+j)*B + b)*50 + (d-71)]; tab = 2 + j; }
        else if (d < 122) { idx = role_idx[(i*2+0)*B + b];                tab = 0;     }
        else if (d < 132) { idx = neg_role[((i*2+0)*B + b)*NS + (d-122)]; tab = 0;     }
        else if (d < 133) { idx = role_idx[(i*2+1)*B + b];                tab = 1;     }
        else if (d < 143) { idx = neg_role[((i*2+1)*B + b)*NS + (d-133)]; tab = 1;     }
        pk[s] = idx | (tab << 20);
    }

    // ---- node embedding fragment: quarter-wave layout, 8 dims/lane ----
    const int l16     = lane & 15;
    const int quarter = lane >> 4;
    const int nrow    = nodes_idx[i*B + b];
    const float4* nep = (const float4*)(node_tables + ((size_t)i*V + (size_t)nrow)*D) + l16*2;
    const float4 ne0 = nep[0];
    const float4 ne1 = nep[1];

    // ---- 4-deep register prefetch pipeline (all indices static via full unroll) ----
    float4 c0b[PIPE], c1b[PIPE];

    auto issue = [&](int t) {
        int s   = t >> 4;
        int src = (4*t + quarter) & 63;
        int p   = __shfl(pk[s], src, 64);
        int idx = p & 0xFFFFF;
        int tab = p >> 20;
        const float* base = (tab & 2) ? neigh_tables : node_tables;
        const float4* row = (const float4*)(base + ((size_t)(tab & 1)*V + (size_t)idx)*D) + l16*2;
        c0b[t & (PIPE-1)] = row[0];
        c1b[t & (PIPE-1)] = row[1];
    };

    float accA = 0.0f, accB = 0.0f, accC = 0.0f, accG = 0.0f;

    #pragma unroll
    for (int t = 0; t < PIPE; ++t) issue(t);

    // d = 4t + quarter. Section -> (class, sign) is compile-time per t except
    // boundary t in {1,13,16,17,30,33,35} which need a per-quarter select.
    #pragma unroll
    for (int t = 0; t < 36; ++t) {
        if (t + PIPE < 36) issue(t + PIPE);
        float4 c0 = c0b[t & (PIPE-1)];
        float4 c1 = c1b[t & (PIPE-1)];
        float pp = ne0.x*c0.x + ne0.y*c0.y + ne0.z*c0.z + ne0.w*c0.w
                 + ne1.x*c1.x + ne1.y*c1.y + ne1.z*c1.z + ne1.w*c1.w;
        // 16-lane reduce, pure VALU (DPP): quad sums then ror4+ror8 rotation
        pp = dpp_xadd<0xB1>(pp);
        pp = dpp_xadd<0x4E>(pp);
        pp = dpp_xadd<0x124>(pp);
        pp = dpp_xadd<0x128>(pp);

        if (t == 0) {                               // d 0..3: A+
            accA += lsig(pp);
        } else if (t == 1) {                        // d 4: A+ | d 5..7: B-
            float x  = (quarter == 0) ? pp : -pp;
            float mw = (quarter == 0) ? W_A : W_B;
            accG = fmaf(mw, lsig(x), accG);
        } else if (t <= 12) {                       // d 8..51: B-
            accB += lsig(-pp);
        } else if (t == 13) {                       // d 52..54: B- | d 55: C+
            float x  = (quarter == 3) ? pp : -pp;
            float mw = (quarter == 3) ? W_C : W_B;
            accG = fmaf(mw, lsig(x), accG);
        } else if (t <= 15) {                       // d 56..63: C-
            accC += lsig(-pp);
        } else if (t == 16) {                       // d 64,65: C- | d 66,67: D+
            float x  = (quarter >= 2) ? pp : -pp;
            float mw = (quarter >= 2) ? W_D : W_C;
            accG = fmaf(mw, lsig(x), accG);
        } else if (t == 17) {                       // d 68..70: D+ | d 71: C-
            float x  = (quarter == 3) ? -pp : pp;
            float mw = (quarter == 3) ? W_C : W_D;
            accG = fmaf(mw, lsig(x), accG);
        } else if (t <= 29) {                       // d 72..119: C-
            accC += lsig(-pp);
        } else if (t == 30) {                       // d 120: C- | 121: C+ | 122,123: C-
            float x = (quarter == 1) ? pp : -pp;
            accC += lsig(x);
        } else if (t <= 32) {                       // d 124..131: C-
            accC += lsig(-pp);
        } else if (t == 33) {                       // d 132: C+ | 133..135: C-
            float x = (quarter == 0) ? pp : -pp;
            accC += lsig(x);
        } else if (t == 34) {                       // d 136..139: C-
            accC += lsig(-pp);
        } else {                                    // t==35: d 140..142: C- | 143: pad
            float ls = lsig(-pp);
            accC += (quarter == 3) ? 0.0f : ls;
        }
    }

    float acc = W_A*accA + W_B*accB + W_C*accC + accG;

    // combine quarters: values identical within each 16-lane row, so xor16+xor32
    // adds exactly one representative from each quarter -> S_unit on all lanes.
    acc += __shfl_xor(acc, 16, 64);
    acc += __shfl_xor(acc, 32, 64);

    __shared__ float wsum[4];
    if (lane == 0) wsum[wave] = acc;
    __syncthreads();
    if (tid == 0) {
        float s = wsum[0] + wsum[1] + wsum[2] + wsum[3];
        atomicAdd(ws + (blockIdx.x & (NBINS - 1)), s);
    }
}

__global__ void rmne_finalize(const float* __restrict__ ws, float* __restrict__ out)
{
    float v = ws[threadIdx.x];
    v += __shfl_xor(v, 1, 64);
    v += __shfl_xor(v, 2, 64);
    v += __shfl_xor(v, 4, 64);
    v += __shfl_xor(v, 8, 64);
    v += __shfl_xor(v, 16, 64);
    v += __shfl_xor(v, 32, 64);
    if (threadIdx.x == 0) out[0] = v * (-1.0f / 10.0f);
}

extern "C" void kernel_launch(void* const* d_in, const int* in_sizes, int n_in,
                              void* d_out, int out_size, void* d_ws, size_t ws_size,
                              hipStream_t stream) {
    const float* node_tables  = (const float*)d_in[0];
    const float* neigh_tables = (const float*)d_in[1];
    const int*   nodes_idx    = (const int*)d_in[2];
    const int*   neigh_idx    = (const int*)d_in[3];
    const int*   role_idx     = (const int*)d_in[4];
    const int*   neg_main     = (const int*)d_in[5];
    const int*   neg_node     = (const int*)d_in[6];
    const int*   neg_cross    = (const int*)d_in[7];
    const int*   neg_role     = (const int*)d_in[8];
    float* ws  = (float*)d_ws;
    float* out = (float*)d_out;

    hipMemsetAsync(ws, 0, NBINS * sizeof(float), stream);
    rmne_main<<<2048, 256, 0, stream>>>(node_tables, neigh_tables, nodes_idx, neigh_idx,
                                        role_idx, neg_main, neg_node, neg_cross, neg_role, ws);
    rmne_finalize<<<1, 64, 0, stream>>>(ws, out);
}